// Round 2
// baseline (118.206 us; speedup 1.0000x reference)
//
#include <hip/hip_runtime.h>

// SGAN_PoolingNet: pooled[i] = max_j relu( relu([hidden[j], (ends[j]-ends[i])@We+be] @ W1 + b1) @ W2 + b2 )
// Collapse: y_lin[i,j,:] = A[j,:] - U[i,:]
//   A[j,k] = hidden[j]@W1[0:64,k] + ends[j]@M2[:,k] + b1[k] + be@W1[64:80,k]   (precomputed f32 math, stored bf16)
//   U[i,k] = ends[i]@M2[:,k],  M2 = We @ W1[64:80,:]  (2x128, f32)
// Main kernel: per agent i, Z = relu(A - U[i]) @ W2 via mfma_f32_16x16x32_bf16, row-max, +b2, relu.
// Dtypes: ALL inputs and the output are float32 (reference is jnp.float32; R1's inf proved the
// bf16-input assumption wrong). Only A and W2 are rounded to bf16 for the MFMA path; accum f32.

#define N_AG 1024

typedef __attribute__((ext_vector_type(8))) short short8;   // 8 bf16 = 4 VGPR (MFMA A/B frag)
typedef __attribute__((ext_vector_type(4))) float floatx4;  // MFMA C/D frag

__device__ __forceinline__ float bf2f(unsigned short u) {
  unsigned v = ((unsigned)u) << 16;
  return __builtin_bit_cast(float, v);
}
__device__ __forceinline__ unsigned short f2bf(float f) {
  unsigned u = __builtin_bit_cast(unsigned, f);
  u += 0x7FFFu + ((u >> 16) & 1u);   // RNE
  return (unsigned short)(u >> 16);
}

// ---- prep 1: M2[c][k] = sum_e We[c,e] * W1[64+e, k]   (1 block x 256 thr, f32) ----
__global__ void prep_m2(const float* __restrict__ We,
                        const float* __restrict__ W1,
                        float* __restrict__ M2f) {
  int t = threadIdx.x;          // 0..255
  int c = t >> 7, k = t & 127;
  float s = 0.f;
#pragma unroll
  for (int e = 0; e < 16; ++e)
    s += We[c * 16 + e] * W1[(64 + e) * 128 + k];
  M2f[c * 128 + k] = s;
}

// ---- prep 2: W2T[n][c] = bf16(W2[c][n])  (64x128) ----
__global__ void prep_w2t(const float* __restrict__ W2,
                         unsigned short* __restrict__ W2T) {
  int idx = blockIdx.x * 256 + threadIdx.x;  // 8192
  int n = idx >> 7, c = idx & 127;
  W2T[n * 128 + c] = f2bf(W2[c * 64 + n]);
}

// ---- prep 3: A[j][k] f32 math -> bf16, one block per j ----
__global__ __launch_bounds__(128) void precompute_A(
    const float* __restrict__ hidden,  // (1,1024,64)
    const float* __restrict__ track,   // (1024,8,2)
    const float* __restrict__ We,      // (2,16)
    const float* __restrict__ be,      // (16)
    const float* __restrict__ W1,      // (80,128)
    const float* __restrict__ b1,      // (128)
    unsigned short* __restrict__ Abf)  // (1024,128) bf16
{
  int j = blockIdx.x;
  int k = threadIdx.x;
  __shared__ float hj[64];
  if (k < 64) hj[k] = hidden[j * 64 + k];
  __syncthreads();
  float e0 = track[j * 16 + 14];
  float e1 = track[j * 16 + 15];
  float m20 = 0.f, m21 = 0.f, cb = b1[k];
#pragma unroll
  for (int t = 0; t < 16; ++t) {
    float w1v = W1[(64 + t) * 128 + k];
    m20 += We[t] * w1v;
    m21 += We[16 + t] * w1v;
    cb  += be[t] * w1v;
  }
  float acc = e0 * m20 + e1 * m21 + cb;
#pragma unroll 16
  for (int t = 0; t < 64; ++t) acc += hj[t] * W1[t * 128 + k];
  Abf[j * 128 + k] = f2bf(acc);
}

// ---- main: one block per agent i, 4 waves split 64 j-tiles ----
__global__ __launch_bounds__(256) void pool_main(
    const unsigned short* __restrict__ Abf,   // (1024,128) bf16
    const float* __restrict__ M2f,            // (2,128) f32
    const float* __restrict__ track,          // (1024,8,2) f32
    const unsigned short* __restrict__ W2T,   // (64,128) bf16
    const float* __restrict__ b2,             // (64) f32
    float* __restrict__ out)                  // (1024,64) f32
{
  const int i    = blockIdx.x;
  const int lane = threadIdx.x & 63;
  const int wave = threadIdx.x >> 6;
  const int m    = lane & 15;   // A row within tile / B-and-D column
  const int quad = lane >> 4;   // k-subrange selector

  // U[i][k] = e0*M2[0][k] + e1*M2[1][k], only the 32 k's this lane needs
  const float e0 = track[i * 16 + 14];
  const float e1 = track[i * 16 + 15];
  float u[4][8];
#pragma unroll
  for (int kk = 0; kk < 4; ++kk) {
#pragma unroll
    for (int jj = 0; jj < 8; ++jj) {
      int k = kk * 32 + quad * 8 + jj;
      u[kk][jj] = e0 * M2f[k] + e1 * M2f[128 + k];
    }
  }

  // B fragments resident in registers: W2T[(t*16+m)][kk*32+quad*8 ..+8)
  short8 bfrag[4][4];
#pragma unroll
  for (int t = 0; t < 4; ++t)
#pragma unroll
    for (int kk = 0; kk < 4; ++kk)
      bfrag[t][kk] = *(const short8*)(W2T + (t * 16 + m) * 128 + kk * 32 + quad * 8);

  floatx4 mx[4];
#pragma unroll
  for (int t = 0; t < 4; ++t) mx[t] = (floatx4){-3e38f, -3e38f, -3e38f, -3e38f};

  for (int jt = wave; jt < 64; jt += 4) {
    const unsigned short* Arow = Abf + (jt * 16 + m) * 128 + quad * 8;
    short8 afrag[4];
#pragma unroll
    for (int kk = 0; kk < 4; ++kk) {
      short8 raw = *(const short8*)(Arow + kk * 32);
#pragma unroll
      for (int jj = 0; jj < 8; ++jj) {
        float a = bf2f((unsigned short)raw[jj]);
        float y = a - u[kk][jj];
        y = y > 0.f ? y : 0.f;
        afrag[kk][jj] = (short)f2bf(y);
      }
    }
#pragma unroll
    for (int t = 0; t < 4; ++t) {
      floatx4 acc = (floatx4){0.f, 0.f, 0.f, 0.f};
#pragma unroll
      for (int kk = 0; kk < 4; ++kk)
        acc = __builtin_amdgcn_mfma_f32_16x16x32_bf16(afrag[kk], bfrag[t][kk], acc, 0, 0, 0);
#pragma unroll
      for (int r = 0; r < 4; ++r) mx[t][r] = fmaxf(mx[t][r], acc[r]);
    }
  }

  // D layout: row = quad*4 + r, col = m. Reduce rows: in-lane (4 rows) then across quads.
  float lm[4];
#pragma unroll
  for (int t = 0; t < 4; ++t) {
    lm[t] = fmaxf(fmaxf(mx[t][0], mx[t][1]), fmaxf(mx[t][2], mx[t][3]));
    lm[t] = fmaxf(lm[t], __shfl_xor(lm[t], 16, 64));
    lm[t] = fmaxf(lm[t], __shfl_xor(lm[t], 32, 64));
  }
  __shared__ float red[4][64];
  if (quad == 0) {
#pragma unroll
    for (int t = 0; t < 4; ++t) red[wave][t * 16 + m] = lm[t];
  }
  __syncthreads();
  if (threadIdx.x < 64) {
    int n = threadIdx.x;
    float v = fmaxf(fmaxf(red[0][n], red[1][n]), fmaxf(red[2][n], red[3][n]));
    v += b2[n];
    v = v > 0.f ? v : 0.f;
    out[i * 64 + n] = v;
  }
}

extern "C" void kernel_launch(void* const* d_in, const int* in_sizes, int n_in,
                              void* d_out, int out_size, void* d_ws, size_t ws_size,
                              hipStream_t stream) {
  const float* hidden = (const float*)d_in[0]; // (1,1024,64)
  const float* track  = (const float*)d_in[1]; // (1024,8,2)
  const float* We     = (const float*)d_in[2]; // (2,16)
  const float* be     = (const float*)d_in[3]; // (16)
  const float* W1     = (const float*)d_in[4]; // (80,128)
  const float* b1     = (const float*)d_in[5]; // (128)
  const float* W2     = (const float*)d_in[6]; // (128,64)
  const float* b2     = (const float*)d_in[7]; // (64)
  float* out = (float*)d_out;

  char* ws = (char*)d_ws;
  unsigned short* Abf = (unsigned short*)ws;              // 1024*128*2 = 256 KiB
  float*          M2f = (float*)(ws + 262144);            // 256*4     = 1 KiB
  unsigned short* W2T = (unsigned short*)(ws + 263168);   // 64*128*2  = 16 KiB

  prep_m2<<<1, 256, 0, stream>>>(We, W1, M2f);
  prep_w2t<<<32, 256, 0, stream>>>(W2, W2T);
  precompute_A<<<N_AG, 128, 0, stream>>>(hidden, track, We, be, W1, b1, Abf);
  pool_main<<<N_AG, 256, 0, stream>>>(Abf, M2f, track, W2T, b2, out);
}

// Round 3
// 114.161 us; speedup vs baseline: 1.0354x; 1.0354x over previous
//
#include <hip/hip_runtime.h>

// SGAN_PoolingNet: pooled[i] = max_j relu( relu([hidden[j], (ends[j]-ends[i])@We+be] @ W1 + b1) @ W2 + b2 )
// Collapse: y_lin[i,j,:] = A[j,:] - U[i,:]
//   A[j,k] = hidden[j]@W1[0:64,k] + ends[j]@M2[:,k] + b1[k] + be@W1[64:80,k]   (f32 math, stored bf16)
//   U[i,k] = ends[i]@M2[:,k],  M2 = We @ W1[64:80,:]  (2x128, f32)
// pool_main: per agent i, Z = relu(A - U[i]) @ W2 via mfma_f32_16x16x32_bf16, row-max, +b2, relu.
// R3: (a) v_cvt_pk_bf16_f32 HW converter cuts repack 8->3.5 instr/elem (the R2 bottleneck:
//     VALUBusy 49%, MfmaUtil 12%); (b) 4 dispatches -> 2 (prep fused; block0's m20/m21 == M2 rows).

#define N_AG 1024

typedef __attribute__((ext_vector_type(8))) short short8;        // 8 bf16 = 4 VGPR (MFMA A/B frag)
typedef __attribute__((ext_vector_type(4))) float floatx4;       // MFMA C/D frag
typedef __attribute__((ext_vector_type(4))) unsigned int uintx4; // 4 packed bf16 pairs

#if defined(__has_builtin)
#if __has_builtin(__builtin_amdgcn_cvt_pk_bf16_f32)
#define HAVE_CVT_PK_BF16 1
typedef __bf16 bf16x2 __attribute__((ext_vector_type(2)));
#endif
#endif

__device__ __forceinline__ unsigned short f2bf(float f) {
  unsigned u = __builtin_bit_cast(unsigned, f);
  u += 0x7FFFu + ((u >> 16) & 1u);   // RNE
  return (unsigned short)(u >> 16);
}

// pack two f32 -> one dword of packed bf16 {lo=y0, hi=y1}, RNE
__device__ __forceinline__ unsigned pack2bf(float y0, float y1) {
#ifdef HAVE_CVT_PK_BF16
  bf16x2 pk = __builtin_amdgcn_cvt_pk_bf16_f32(y0, y1);
  return __builtin_bit_cast(unsigned, pk);
#else
  return (unsigned)f2bf(y0) | ((unsigned)f2bf(y1) << 16);
#endif
}

// ---- prep (fused): block j computes A[j]; block 0 writes M2; blocks 0..31 write W2T ----
__global__ __launch_bounds__(128) void prep_all(
    const float* __restrict__ hidden,  // (1,1024,64)
    const float* __restrict__ track,   // (1024,8,2)
    const float* __restrict__ We,      // (2,16)
    const float* __restrict__ be,      // (16)
    const float* __restrict__ W1,      // (80,128)
    const float* __restrict__ b1,      // (128)
    const float* __restrict__ W2,      // (128,64)
    unsigned short* __restrict__ Abf,  // (1024,128) bf16
    float* __restrict__ M2f,           // (2,128) f32
    unsigned short* __restrict__ W2T)  // (64,128) bf16
{
  int j = blockIdx.x;
  int k = threadIdx.x;   // 0..127
  __shared__ float hj[64];
  if (k < 64) hj[k] = hidden[j * 64 + k];
  __syncthreads();
  float e0 = track[j * 16 + 14];
  float e1 = track[j * 16 + 15];
  float m20 = 0.f, m21 = 0.f, cb = b1[k];
#pragma unroll
  for (int t = 0; t < 16; ++t) {
    float w1v = W1[(64 + t) * 128 + k];
    m20 += We[t] * w1v;
    m21 += We[16 + t] * w1v;
    cb  += be[t] * w1v;
  }
  float acc = e0 * m20 + e1 * m21 + cb;
#pragma unroll 16
  for (int t = 0; t < 64; ++t) acc += hj[t] * W1[t * 128 + k];
  Abf[j * 128 + k] = f2bf(acc);

  if (j == 0) {           // m20/m21 are exactly M2[0][k], M2[1][k]
    M2f[k]       = m20;
    M2f[128 + k] = m21;
  }
  if (j < 32) {           // W2T[n][c] = bf16(W2[c][n]); 32 blocks x 256 entries
#pragma unroll
    for (int q = 0; q < 2; ++q) {
      int idx = j * 256 + q * 128 + k;
      int n = idx >> 7, c = idx & 127;
      W2T[n * 128 + c] = f2bf(W2[c * 64 + n]);
    }
  }
}

// ---- main: one block per agent i, 4 waves split 64 j-tiles ----
__global__ __launch_bounds__(256) void pool_main(
    const unsigned short* __restrict__ Abf,   // (1024,128) bf16
    const float* __restrict__ M2f,            // (2,128) f32
    const float* __restrict__ track,          // (1024,8,2) f32
    const unsigned short* __restrict__ W2T,   // (64,128) bf16
    const float* __restrict__ b2,             // (64) f32
    float* __restrict__ out)                  // (1024,64) f32
{
  const int i    = blockIdx.x;
  const int lane = threadIdx.x & 63;
  const int wave = threadIdx.x >> 6;
  const int m    = lane & 15;   // A row within tile / B-and-D column
  const int quad = lane >> 4;   // k-subrange selector

  // U[i][k] for the 32 k's this lane touches
  const float e0 = track[i * 16 + 14];
  const float e1 = track[i * 16 + 15];
  float u[4][8];
#pragma unroll
  for (int kk = 0; kk < 4; ++kk) {
#pragma unroll
    for (int jj = 0; jj < 8; ++jj) {
      int kidx = kk * 32 + quad * 8 + jj;
      u[kk][jj] = e0 * M2f[kidx] + e1 * M2f[128 + kidx];
    }
  }

  // B fragments resident in registers
  short8 bfrag[4][4];
#pragma unroll
  for (int t = 0; t < 4; ++t)
#pragma unroll
    for (int kk = 0; kk < 4; ++kk)
      bfrag[t][kk] = *(const short8*)(W2T + (t * 16 + m) * 128 + kk * 32 + quad * 8);

  floatx4 mx[4];
#pragma unroll
  for (int t = 0; t < 4; ++t) mx[t] = (floatx4){-3e38f, -3e38f, -3e38f, -3e38f};

  for (int jt = wave; jt < 64; jt += 4) {
    const unsigned short* Aptr = Abf + (jt * 16 + m) * 128 + quad * 8;
    uintx4 au[4];
#pragma unroll
    for (int kk = 0; kk < 4; ++kk) {
      uintx4 raw = *(const uintx4*)(Aptr + kk * 32);
#pragma unroll
      for (int p = 0; p < 4; ++p) {
        unsigned w = raw[p];
        float lo = __builtin_bit_cast(float, w << 16);          // element 2p   (low half)
        float hi = __builtin_bit_cast(float, w & 0xFFFF0000u);  // element 2p+1 (high half)
        float y0 = fmaxf(lo - u[kk][2 * p], 0.f);
        float y1 = fmaxf(hi - u[kk][2 * p + 1], 0.f);
        au[kk][p] = pack2bf(y0, y1);
      }
    }
#pragma unroll
    for (int t = 0; t < 4; ++t) {
      floatx4 acc = (floatx4){0.f, 0.f, 0.f, 0.f};
#pragma unroll
      for (int kk = 0; kk < 4; ++kk) {
        short8 af = __builtin_bit_cast(short8, au[kk]);
        acc = __builtin_amdgcn_mfma_f32_16x16x32_bf16(af, bfrag[t][kk], acc, 0, 0, 0);
      }
#pragma unroll
      for (int r = 0; r < 4; ++r) mx[t][r] = fmaxf(mx[t][r], acc[r]);
    }
  }

  // D layout: row = quad*4 + r, col = m. In-lane (4 rows) then across quads; cross-wave via LDS.
  float lm[4];
#pragma unroll
  for (int t = 0; t < 4; ++t) {
    lm[t] = fmaxf(fmaxf(mx[t][0], mx[t][1]), fmaxf(mx[t][2], mx[t][3]));
    lm[t] = fmaxf(lm[t], __shfl_xor(lm[t], 16, 64));
    lm[t] = fmaxf(lm[t], __shfl_xor(lm[t], 32, 64));
  }
  __shared__ float red[4][64];
  if (quad == 0) {
#pragma unroll
    for (int t = 0; t < 4; ++t) red[wave][t * 16 + m] = lm[t];
  }
  __syncthreads();
  if (threadIdx.x < 64) {
    int n = threadIdx.x;
    float v = fmaxf(fmaxf(red[0][n], red[1][n]), fmaxf(red[2][n], red[3][n]));
    v += b2[n];
    v = v > 0.f ? v : 0.f;
    out[i * 64 + n] = v;
  }
}

extern "C" void kernel_launch(void* const* d_in, const int* in_sizes, int n_in,
                              void* d_out, int out_size, void* d_ws, size_t ws_size,
                              hipStream_t stream) {
  const float* hidden = (const float*)d_in[0]; // (1,1024,64)
  const float* track  = (const float*)d_in[1]; // (1024,8,2)
  const float* We     = (const float*)d_in[2]; // (2,16)
  const float* be     = (const float*)d_in[3]; // (16)
  const float* W1     = (const float*)d_in[4]; // (80,128)
  const float* b1     = (const float*)d_in[5]; // (128)
  const float* W2     = (const float*)d_in[6]; // (128,64)
  const float* b2     = (const float*)d_in[7]; // (64)
  float* out = (float*)d_out;

  char* ws = (char*)d_ws;
  unsigned short* Abf = (unsigned short*)ws;              // 1024*128*2 = 256 KiB
  float*          M2f = (float*)(ws + 262144);            // 256*4     = 1 KiB
  unsigned short* W2T = (unsigned short*)(ws + 263168);   // 64*128*2  = 16 KiB

  prep_all<<<N_AG, 128, 0, stream>>>(hidden, track, We, be, W1, b1, W2, Abf, M2f, W2T);
  pool_main<<<N_AG, 256, 0, stream>>>(Abf, M2f, track, W2T, b2, out);
}